// Round 13
// baseline (991.282 us; speedup 1.0000x reference)
//
#include <hip/hip_runtime.h>
#include <stdint.h>

#define NN 20000
#define NE 160000
#define L_IN 15
#define D_H 128
#define N_HEADS 8
#define D_HC 1024
#define N_LAYERS 6
#define M_PAD 20096   // 157*128 = 1250*16 + pad
#define QS2 2048      // zd|x_r interleaved row stride (u overwrites zd slot)

typedef unsigned short u16;
typedef __attribute__((ext_vector_type(8))) short short8;
typedef __attribute__((ext_vector_type(4))) float f32x4;

#define RSQRT_D 0.08838834764831845f  // 1/sqrt(128)

__device__ __forceinline__ float bu2f(u16 u) { return __uint_as_float(((unsigned)u) << 16); }
__device__ __forceinline__ u16 f2bu(float f) {
    unsigned x = __float_as_uint(f);
    return (u16)((x + 0x7fffu + ((x >> 16) & 1u)) >> 16);  // RNE
}
__device__ __forceinline__ float wred64(float v) {
#pragma unroll
    for (int m = 32; m >= 1; m >>= 1) v += __shfl_xor(v, m, 64);
    return v;
}
__device__ __forceinline__ void cvt16(const uint4& u0, const uint4& u1, float* f) {
    unsigned d[8] = {u0.x, u0.y, u0.z, u0.w, u1.x, u1.y, u1.z, u1.w};
#pragma unroll
    for (int i = 0; i < 8; i++) {
        f[2 * i]     = __uint_as_float(d[i] << 16);
        f[2 * i + 1] = __uint_as_float(d[i] & 0xffff0000u);
    }
}

// ---------------- dtype detection ----------------
__global__ void k_detect(const u16* __restrict__ xb, int* __restrict__ flag) {
    int t = threadIdx.x;
    u16 u = xb[2 * t];
    int e = (u >> 7) & 0xFF;
    int weird = (e > 150 || (e != 0 && e < 100)) ? 1 : 0;
    __shared__ int cnt;
    if (t == 0) cnt = 0;
    __syncthreads();
    atomicAdd(&cnt, weird);
    __syncthreads();
    if (t == 0) *flag = (cnt > 64) ? 1 : 0;  // 1 = inputs are fp32
}

// ---------------- fused convert (13 segments incl. Wq, Wk) ----------------
struct CvDesc { const void* in[13]; u16* out[13]; };
#define CV_TOTAL 1930976
__global__ void k_convert_all(CvDesc dsc, const int* __restrict__ flag) {
    const int sizes[13] = {NN * L_IN, L_IN * D_H, D_H,
                           N_LAYERS * D_HC, N_LAYERS * D_HC, N_LAYERS * D_HC,
                           N_LAYERS * D_HC, N_LAYERS * 3 * D_HC,
                           N_LAYERS * D_HC, N_LAYERS * D_HC, N_LAYERS * D_H,
                           N_LAYERS * D_H * D_HC, N_LAYERS * D_H * D_HC};
    int off = blockIdx.x * 256 + threadIdx.x;
    if (off >= CV_TOTAL) return;
    int seg = 0;
#pragma unroll
    for (int s = 0; s < 13; s++) {
        if (off >= sizes[s] && seg == s) { off -= sizes[s]; seg = s + 1; }
    }
    if (*flag) dsc.out[seg][off] = f2bu(((const float*)dsc.in[seg])[off]);
    else       dsc.out[seg][off] = ((const u16*)dsc.in[seg])[off];
}

__global__ void k_zero(int* __restrict__ p, int n) {
    int i = blockIdx.x * 256 + threadIdx.x;
    if (i < n) p[i] = 0;
}

// ------------- convert+transpose: Wv -> WvT, Wskip -> Bmain rows 1024.. ------
__global__ void k_convT_vs(const void* __restrict__ Wv, const void* __restrict__ Ws,
                           u16* __restrict__ WvT, u16* __restrict__ Bmain,
                           const int* __restrict__ flag) {
    __shared__ u16 tile[64][66];
    int tk = blockIdx.x, tn = blockIdx.y, l = blockIdx.z;
    int t = threadIdx.x;
    int isv = (tn < 16);
    const void* W = isv ? Wv : Ws;
    int n_off = (tn & 15) * 64;
    int r = t >> 2, c0 = (t & 3) * 16;
    size_t base = (size_t)l * 128 * 1024 + (size_t)(tk * 64 + r) * 1024 + n_off + c0;
    if (*flag) {
        const float* Wf = (const float*)W;
#pragma unroll
        for (int cc = 0; cc < 16; cc++) tile[c0 + cc][r] = f2bu(Wf[base + cc]);
    } else {
        const u16* Wh = (const u16*)W;
#pragma unroll
        for (int cc = 0; cc < 16; cc++) tile[c0 + cc][r] = Wh[base + cc];
    }
    __syncthreads();
    int i = t >> 2, j0 = (t & 3) * 16;
    u16* dst = isv ? (WvT + ((size_t)l * 1024 + n_off + i) * 128 + tk * 64 + j0)
                   : (Bmain + ((size_t)l * 2048 + 1024 + n_off + i) * 128 + tk * 64 + j0);
#pragma unroll
    for (int jj = 0; jj < 16; jj++) dst[jj] = tile[i][j0 + jj];
}

// Wp: [l][1024 k][128 n] -> WTp [l][128 n][1024 k]. grid (16, 2, 6).
__global__ void k_convT_proj(const void* __restrict__ Wp, u16* __restrict__ WT,
                             const int* __restrict__ flag) {
    __shared__ u16 tile[64][66];
    int tk = blockIdx.x, tn = blockIdx.y, l = blockIdx.z;
    int t = threadIdx.x;
    int r = t >> 2, c0 = (t & 3) * 16;
    size_t base = (size_t)l * 1024 * 128 + (size_t)(tk * 64 + r) * 128 + tn * 64 + c0;
    if (*flag) {
        const float* Wf = (const float*)Wp;
#pragma unroll
        for (int cc = 0; cc < 16; cc++) tile[c0 + cc][r] = f2bu(Wf[base + cc]);
    } else {
        const u16* Wh = (const u16*)Wp;
#pragma unroll
        for (int cc = 0; cc < 16; cc++) tile[c0 + cc][r] = Wh[base + cc];
    }
    __syncthreads();
    int i = t >> 2, j0 = (t & 3) * 16;
    u16* dst = WT + ((size_t)l * 128 + tn * 64 + i) * 1024 + tk * 64 + j0;
#pragma unroll
    for (int jj = 0; jj < 16; jj++) dst[jj] = tile[i][j0 + jj];
}

// ---------------- GG precompute: Bmain rows 0-1023 = (Wq_h Wk_h^T)^T / sqrt(d) --
__global__ void k_GG(const u16* __restrict__ Wqb, const u16* __restrict__ Wkb,
                     u16* __restrict__ Bmain) {
    int h = blockIdx.x, l = blockIdx.y;
    __shared__ __align__(16) u16 Als[128 * 32];
    __shared__ __align__(16) u16 Bls[128 * 32];
    const int t = threadIdx.x;
    const int wave = t >> 6, lane = t & 63, quad = lane >> 4, l16 = lane & 15;
    const int wm = (wave >> 1) * 64, wn = (wave & 1) * 64;
    const u16* Ab = Wqb + (size_t)l * 128 * 1024 + h * 128;
    const u16* Bb = Wkb + (size_t)l * 128 * 1024 + h * 128;
    f32x4 acc[4][4];
#pragma unroll
    for (int i = 0; i < 4; i++)
#pragma unroll
        for (int j = 0; j < 4; j++) acc[i][j] = (f32x4){0.f, 0.f, 0.f, 0.f};
    for (int ko = 0; ko < 128; ko += 32) {
#pragma unroll
        for (int c = t; c < 512; c += 256) {
            int row = c >> 2, kc = c & 3;
            *reinterpret_cast<uint4*>(&Als[row * 32 + kc * 8]) =
                *reinterpret_cast<const uint4*>(Ab + (size_t)row * 1024 + ko + kc * 8);
            *reinterpret_cast<uint4*>(&Bls[row * 32 + kc * 8]) =
                *reinterpret_cast<const uint4*>(Bb + (size_t)row * 1024 + ko + kc * 8);
        }
        __syncthreads();
        short8 af[4], bf[4];
#pragma unroll
        for (int mt = 0; mt < 4; mt++)
            af[mt] = *reinterpret_cast<const short8*>(&Als[(wm + mt * 16 + l16) * 32 + quad * 8]);
#pragma unroll
        for (int nt = 0; nt < 4; nt++)
            bf[nt] = *reinterpret_cast<const short8*>(&Bls[(wn + nt * 16 + l16) * 32 + quad * 8]);
#pragma unroll
        for (int mt = 0; mt < 4; mt++)
#pragma unroll
            for (int nt = 0; nt < 4; nt++)
                acc[mt][nt] = __builtin_amdgcn_mfma_f32_16x16x32_bf16(af[mt], bf[nt], acc[mt][nt], 0, 0, 0);
        __syncthreads();
    }
    u16* dst = Bmain + (size_t)l * 2048 * 128;
#pragma unroll
    for (int mt = 0; mt < 4; mt++)
#pragma unroll
        for (int r = 0; r < 4; r++) {
            int row = wm + mt * 16 + quad * 4 + r;  // a
#pragma unroll
            for (int nt = 0; nt < 4; nt++) {
                int col = wn + nt * 16 + l16;       // b
                dst[(size_t)(h * 128 + col) * 128 + row] = f2bu(acc[mt][nt][r] * RSQRT_D);
            }
        }
}

// ---------------- small precompute: cb, wscT ([h][a] layout), csc ----------------
__global__ void k_pre_small(const u16* __restrict__ Wqb, const u16* __restrict__ Wkb,
                            const u16* __restrict__ bq, const u16* __restrict__ bk,
                            u16* __restrict__ cb, float* __restrict__ wscT,
                            float* __restrict__ csc) {
    int gid = blockIdx.x * 256 + threadIdx.x;  // 6*2056
    if (gid >= N_LAYERS * 2056) return;
    int l = gid / 2056, r = gid % 2056;
    float acc = 0.f;
    if (r < 1024) {
        int h = r >> 7, b = r & 127;
        const u16* bqp = bq + l * D_HC + h * 128;
        const u16* wkp = Wkb + (size_t)l * 128 * 1024 + (size_t)b * 1024 + h * 128;
        for (int m = 0; m < 128; m++) acc += bu2f(bqp[m]) * bu2f(wkp[m]);
        cb[l * 1024 + r] = f2bu(acc * RSQRT_D);
    } else if (r < 2048) {
        int idx = r - 1024;          // idx = h*128 + a
        int h = idx >> 7, a = idx & 127;
        const u16* wqp = Wqb + (size_t)l * 128 * 1024 + (size_t)a * 1024 + h * 128;
        const u16* bkp = bk + l * D_HC + h * 128;
        for (int m = 0; m < 128; m++) acc += bu2f(wqp[m]) * bu2f(bkp[m]);
        wscT[l * 1024 + idx] = acc * RSQRT_D;
    } else {
        int h = r - 2048;
        const u16* bqp = bq + l * D_HC + h * 128;
        const u16* bkp = bk + l * D_HC + h * 128;
        for (int m = 0; m < 128; m++) acc += bu2f(bqp[m]) * bu2f(bkp[m]);
        csc[l * 8 + h] = acc * RSQRT_D;
    }
}

// ---------------- input projection ----------------
__global__ void k_input_proj(const u16* __restrict__ x, const u16* __restrict__ Win,
                             const u16* __restrict__ b_in, u16* __restrict__ h) {
    int gid = blockIdx.x * 256 + threadIdx.x;  // NN*128
    int n = gid >> 7, j = gid & 127;
    float acc = bu2f(b_in[j]);
#pragma unroll
    for (int i = 0; i < L_IN; i++) acc += bu2f(x[n * L_IN + i]) * bu2f(Win[i * D_H + j]);
    h[gid] = f2bu(acc);
}

// ---------------- CSR build ----------------
__global__ void k_hist(const int* __restrict__ dst, int* __restrict__ cnt) {
    int e = blockIdx.x * 256 + threadIdx.x;
    if (e < NE) atomicAdd(&cnt[dst[e]], 1);
}
__global__ void k_scanA(const int* __restrict__ cnt, int* __restrict__ incl, int* __restrict__ bsum) {
    __shared__ int s[256];
    int b = blockIdx.x, t = threadIdx.x, i = b * 256 + t;
    int v = (i < NN) ? cnt[i] : 0;
    s[t] = v;
    __syncthreads();
    for (int off = 1; off < 256; off <<= 1) {
        int u = (t >= off) ? s[t - off] : 0;
        __syncthreads();
        s[t] += u;
        __syncthreads();
    }
    if (i < NN) incl[i] = s[t];
    if (t == 255) bsum[b] = s[255];
}
__global__ void k_scanB(const int* __restrict__ bsum, int* __restrict__ bpre, int nb) {
    __shared__ int s[128];
    int t = threadIdx.x;
    int v = (t < nb) ? bsum[t] : 0;
    s[t] = v;
    __syncthreads();
    for (int off = 1; off < 128; off <<= 1) {
        int u = (t >= off) ? s[t - off] : 0;
        __syncthreads();
        s[t] += u;
        __syncthreads();
    }
    if (t < nb) bpre[t] = s[t] - v;
}
__global__ void k_scanC(const int* __restrict__ incl, const int* __restrict__ bpre, int* __restrict__ offs) {
    int b = blockIdx.x, t = threadIdx.x, i = b * 256 + t;
    if (i < NN) offs[i + 1] = incl[i] + bpre[b];
    if (i == 0) offs[0] = 0;
}
__global__ void k_scatter(const int* __restrict__ dst, const int* __restrict__ src,
                          const int* __restrict__ offs, int* __restrict__ cursor,
                          int* __restrict__ srcp) {
    int e = blockIdx.x * 256 + threadIdx.x;
    if (e < NE) {
        int d = dst[e];
        int p = offs[d] + atomicAdd(&cursor[d], 1);
        srcp[p] = src[e];
    }
}

// ---------------- main MFMA GEMM: C[M,2048] = h @ [GG^T | WskipT]^T + [cb|bskip] --
__global__ void k_gemm(const u16* __restrict__ A, int lda, int K,
                       const u16* __restrict__ Bt,
                       u16* __restrict__ C, int ldc,
                       const u16* __restrict__ bia0, const u16* __restrict__ bia1) {
    __shared__ __align__(16) u16 smem[128 * 136];
    u16* Als = smem;
    u16* Bls = smem + 4096;
    const int m0 = blockIdx.y * 128, n0 = blockIdx.x * 128;
    const int t = threadIdx.x;
    const int wave = t >> 6, lane = t & 63, quad = lane >> 4, l16 = lane & 15;
    const int wm = (wave >> 1) * 64, wn = (wave & 1) * 64;
    f32x4 acc[4][4];
#pragma unroll
    for (int i = 0; i < 4; i++)
#pragma unroll
        for (int j = 0; j < 4; j++) acc[i][j] = (f32x4){0.f, 0.f, 0.f, 0.f};

    for (int ko = 0; ko < K; ko += 32) {
#pragma unroll
        for (int c = t; c < 512; c += 256) {
            int row = c >> 2, kc = c & 3;
            *reinterpret_cast<uint4*>(&Als[row * 32 + kc * 8]) =
                *reinterpret_cast<const uint4*>(A + (size_t)(m0 + row) * lda + ko + kc * 8);
            *reinterpret_cast<uint4*>(&Bls[row * 32 + kc * 8]) =
                *reinterpret_cast<const uint4*>(Bt + (size_t)(n0 + row) * K + ko + kc * 8);
        }
        __syncthreads();
        short8 af[4], bf[4];
#pragma unroll
        for (int mt = 0; mt < 4; mt++)
            af[mt] = *reinterpret_cast<const short8*>(&Als[(wm + mt * 16 + l16) * 32 + quad * 8]);
#pragma unroll
        for (int nt = 0; nt < 4; nt++)
            bf[nt] = *reinterpret_cast<const short8*>(&Bls[(wn + nt * 16 + l16) * 32 + quad * 8]);
#pragma unroll
        for (int mt = 0; mt < 4; mt++)
#pragma unroll
            for (int nt = 0; nt < 4; nt++)
                acc[mt][nt] = __builtin_amdgcn_mfma_f32_16x16x32_bf16(af[mt], bf[nt], acc[mt][nt], 0, 0, 0);
        __syncthreads();
    }
#pragma unroll
    for (int mt = 0; mt < 4; mt++)
#pragma unroll
        for (int r = 0; r < 4; r++) {
            int rl = wm + mt * 16 + quad * 4 + r;
#pragma unroll
            for (int nt = 0; nt < 4; nt++) {
                int cl = wn + nt * 16 + l16;
                int col = n0 + cl;
                const u16* bp = (col < 1024) ? bia0 : bia1;
                smem[rl * 136 + cl] = f2bu(acc[mt][nt][r] + bu2f(bp[col & 1023]));
            }
        }
    __syncthreads();
#pragma unroll
    for (int c = t; c < 2048; c += 256) {
        int row = c >> 4, kc = c & 15;
        int grow = m0 + row;
        if (grow < NN)
            *reinterpret_cast<uint4*>(C + (size_t)grow * ldc + n0 + kc * 8) =
                *reinterpret_cast<const uint4*>(&smem[row * 136 + kc * 8]);
    }
}

// ---------------- attention (sc inlined): one wave per dst node ----------------
__global__ void k_attn2(u16* __restrict__ qkvs2, const u16* __restrict__ hc,
                        const int* __restrict__ offs, const int* __restrict__ srcp,
                        const float* __restrict__ wscT_l, const float* __restrict__ csc_l) {
    int gid = blockIdx.x * 256 + threadIdx.x;
    int d = gid >> 6, lane = gid & 63;
    if (d >= NN) return;
    int hh = lane >> 3, ci = (lane & 7) * 16;
    u16* zp = qkvs2 + (size_t)d * QS2 + hh * 128 + ci;
    float zf[16];
    {
        uint4 z0 = *reinterpret_cast<const uint4*>(zp);
        uint4 z1 = *reinterpret_cast<const uint4*>(zp + 8);
        cvt16(z0, z1, zf);
    }
    // inline sc: scown = csc[h] + sum_a h_d[a] * wscT[h][a]
    float scown;
    {
        const u16* hdp = hc + (size_t)d * 128 + ci;
        uint4 hd0 = *reinterpret_cast<const uint4*>(hdp);
        uint4 hd1 = *reinterpret_cast<const uint4*>(hdp + 8);
        float hdf[16];
        cvt16(hd0, hd1, hdf);
        const float* wt = wscT_l + hh * 128 + ci;
        float scp = 0.f;
#pragma unroll
        for (int j = 0; j < 16; j++) scp += hdf[j] * wt[j];
        scp += __shfl_xor(scp, 1, 64);
        scp += __shfl_xor(scp, 2, 64);
        scp += __shfl_xor(scp, 4, 64);
        scown = scp + csc_l[hh];
    }
    float u[16];
#pragma unroll
    for (int j = 0; j < 16; j++) u[j] = 0.f;
    float lrun = 0.f;

    int beg = offs[d], end = offs[d + 1];
    for (int c0 = beg; c0 < end; c0 += 64) {
        int cn = min(64, end - c0);
        int myidx = (c0 + lane < end) ? srcp[c0 + lane] : 0;
        int s = __shfl(myidx, 0, 64);
        const u16* hp = hc + (size_t)s * 128 + ci;
        uint4 a0 = *reinterpret_cast<const uint4*>(hp);
        uint4 a1 = *reinterpret_cast<const uint4*>(hp + 8);
        for (int i = 0; i < cn; i++) {
            uint4 n0 = a0, n1 = a1;
            if (i + 1 < cn) {
                int sn = __shfl(myidx, i + 1, 64);
                const u16* hpn = hc + (size_t)sn * 128 + ci;
                n0 = *reinterpret_cast<const uint4*>(hpn);
                n1 = *reinterpret_cast<const uint4*>(hpn + 8);
            }
            float hf[16];
            cvt16(a0, a1, hf);
            float p = 0.f;
#pragma unroll
            for (int j = 0; j < 16; j++) p += zf[j] * hf[j];
            p += __shfl_xor(p, 1, 64);
            p += __shfl_xor(p, 2, 64);
            p += __shfl_xor(p, 4, 64);
            float w = __expf(p + scown);
            lrun += w;
#pragma unroll
            for (int j = 0; j < 16; j++) u[j] += w * hf[j];
            a0 = n0; a1 = n1;
        }
    }
    float inv = 1.f / (lrun + 1e-16f);
    unsigned out[8];
#pragma unroll
    for (int j = 0; j < 8; j++)
        out[j] = (unsigned)f2bu(u[2 * j] * inv) | ((unsigned)f2bu(u[2 * j + 1] * inv) << 16);
    uint4* op = reinterpret_cast<uint4*>(zp);
    op[0] = make_uint4(out[0], out[1], out[2], out[3]);
    op[1] = make_uint4(out[4], out[5], out[6], out[7]);
}

// ---------------- vproj: o[d, h*128+c'] = u[d,h,:] @ Wv_h + bv ----------------
__global__ void k_vproj(const u16* __restrict__ A /*qkvs2 u-slot*/,
                        const u16* __restrict__ WvT_l, const u16* __restrict__ bv_l,
                        u16* __restrict__ obuf) {
    __shared__ __align__(16) u16 smem[128 * 136];
    u16* Als = smem;
    u16* Bls = smem + 4096;
    const int m0 = blockIdx.x * 128, h = blockIdx.y;
    const int t = threadIdx.x;
    const int wave = t >> 6, lane = t & 63, quad = lane >> 4, l16 = lane & 15;
    const int wm = (wave >> 1) * 64, wn = (wave & 1) * 64;
    f32x4 acc[4][4];
#pragma unroll
    for (int i = 0; i < 4; i++)
#pragma unroll
        for (int j = 0; j < 4; j++) acc[i][j] = (f32x4){0.f, 0.f, 0.f, 0.f};

    for (int ko = 0; ko < 128; ko += 32) {
#pragma unroll
        for (int c = t; c < 512; c += 256) {
            int row = c >> 2, kc = c & 3;
            *reinterpret_cast<uint4*>(&Als[row * 32 + kc * 8]) =
                *reinterpret_cast<const uint4*>(A + (size_t)(m0 + row) * QS2 + h * 128 + ko + kc * 8);
            *reinterpret_cast<uint4*>(&Bls[row * 32 + kc * 8]) =
                *reinterpret_cast<const uint4*>(WvT_l + (size_t)(h * 128 + row) * 128 + ko + kc * 8);
        }
        __syncthreads();
        short8 af[4], bf[4];
#pragma unroll
        for (int mt = 0; mt < 4; mt++)
            af[mt] = *reinterpret_cast<const short8*>(&Als[(wm + mt * 16 + l16) * 32 + quad * 8]);
#pragma unroll
        for (int nt = 0; nt < 4; nt++)
            bf[nt] = *reinterpret_cast<const short8*>(&Bls[(wn + nt * 16 + l16) * 32 + quad * 8]);
#pragma unroll
        for (int mt = 0; mt < 4; mt++)
#pragma unroll
            for (int nt = 0; nt < 4; nt++)
                acc[mt][nt] = __builtin_amdgcn_mfma_f32_16x16x32_bf16(af[mt], bf[nt], acc[mt][nt], 0, 0, 0);
        __syncthreads();
    }
#pragma unroll
    for (int mt = 0; mt < 4; mt++)
#pragma unroll
        for (int r = 0; r < 4; r++) {
            int rl = wm + mt * 16 + quad * 4 + r;
#pragma unroll
            for (int nt = 0; nt < 4; nt++) {
                int cl = wn + nt * 16 + l16;
                smem[rl * 136 + cl] = f2bu(acc[mt][nt][r] + bu2f(bv_l[h * 128 + cl]));
            }
        }
    __syncthreads();
#pragma unroll
    for (int c = t; c < 2048; c += 256) {
        int row = c >> 4, kc = c & 15;
        int grow = m0 + row;
        if (grow < NN)
            *reinterpret_cast<uint4*>(obuf + (size_t)grow * 1024 + h * 128 + kc * 8) =
                *reinterpret_cast<const uint4*>(&smem[row * 136 + kc * 8]);
    }
}

// ------- fused betaLN + proj GEMM: y kept in LDS, never touches global -------
// 16-row blocks (1250 = NN/16 exactly). Phase 1: per-wave betaLN for 4 rows
// (reads o from obuf, x_r from qkvs2) -> yls. Phase 2: C[16,128] =
// y @ WTp^T + bias + resid, relu. B-tile register-prefetched; y round-trip
// (82 MB/layer) eliminated.
#define PLDA 40
#define YLD 1032   // u16 stride; 516 words % 32 = 4 -> 2-way conflicts (free)
__global__ void k_bproj(const u16* __restrict__ obuf, const u16* __restrict__ qkvs2,
                        const u16* __restrict__ Wb, const u16* __restrict__ lng,
                        const u16* __restrict__ lnb,
                        const u16* __restrict__ Bt /*WTp layer*/,
                        void* __restrict__ C, int mode,
                        const u16* __restrict__ bias, const u16* __restrict__ resid,
                        const int* __restrict__ flag) {
    __shared__ __align__(16) u16 yls[16 * YLD];   // 33 KB
    __shared__ __align__(16) u16 Bls[128 * PLDA]; // 10 KB
    const int m0 = blockIdx.x * 16;
    const int t = threadIdx.x;
    const int wave = t >> 6, lane = t & 63, quad = lane >> 4, l16 = lane & 15;
    const int fp32out = (mode == 2 && *flag) ? 1 : 0;

    // issue first B-tile prefetch immediately (in flight during phase 1)
    uint4 pb0, pb1;
    const int b0row = t >> 2, bkc = t & 3;
    const int b1row = (t + 256) >> 2;
    pb0 = *reinterpret_cast<const uint4*>(Bt + (size_t)b0row * 1024 + bkc * 8);
    pb1 = *reinterpret_cast<const uint4*>(Bt + (size_t)b1row * 1024 + bkc * 8);

    // ---- phase 1: betaLN for rows wave*4 .. wave*4+3 into yls ----
    {
        int c0 = lane * 16;
        // per-lane weight slices are row-invariant: load once
        float wf1[16], wf2[16], wf3[16], lgf[16], lbf[16];
        {
            const u16* wp = Wb + c0;
            uint4 u0 = *reinterpret_cast<const uint4*>(wp);
            uint4 u1 = *reinterpret_cast<const uint4*>(wp + 8);
            cvt16(u0, u1, wf1);
            u0 = *reinterpret_cast<const uint4*>(wp + D_HC);
            u1 = *reinterpret_cast<const uint4*>(wp + D_HC + 8);
            cvt16(u0, u1, wf2);
            u0 = *reinterpret_cast<const uint4*>(wp + 2 * D_HC);
            u1 = *reinterpret_cast<const uint4*>(wp + 2 * D_HC + 8);
            cvt16(u0, u1, wf3);
            u0 = *reinterpret_cast<const uint4*>(lng + c0);
            u1 = *reinterpret_cast<const uint4*>(lng + c0 + 8);
            cvt16(u0, u1, lgf);
            u0 = *reinterpret_cast<const uint4*>(lnb + c0);
            u1 = *reinterpret_cast<const uint4*>(lnb + c0 + 8);
            cvt16(u0, u1, lbf);
        }
        for (int rr = 0; rr < 4; rr++) {
            int row = wave * 4 + rr;
            int d = m0 + row;
            float o[16], xr[16];
            {
                const u16* op = obuf + (size_t)d * 1024 + c0;
                uint4 o0 = *reinterpret_cast<const uint4*>(op);
                uint4 o1 = *reinterpret_cast<const uint4*>(op + 8);
                cvt16(o0, o1, o);
                const u16* xp = qkvs2 + (size_t)d * QS2 + 1024 + c0;
                uint4 x0 = *reinterpret_cast<const uint4*>(xp);
                uint4 x1 = *reinterpret_cast<const uint4*>(xp + 8);
                cvt16(x0, x1, xr);
            }
            float part = 0.f;
#pragma unroll
            for (int j = 0; j < 16; j++)
                part += o[j] * wf1[j] + xr[j] * wf2[j] + (o[j] - xr[j]) * wf3[j];
            float logit = wred64(part);
            float beta = 1.f / (1.f + __expf(-logit));
            float g[16], s1 = 0.f, s2 = 0.f;
#pragma unroll
            for (int j = 0; j < 16; j++) {
                g[j] = beta * xr[j] + (1.f - beta) * o[j];
                s1 += g[j]; s2 += g[j] * g[j];
            }
            s1 = wred64(s1);
            s2 = wred64(s2);
            float mu = s1 * (1.f / 1024.f);
            float var = s2 * (1.f / 1024.f) - mu * mu;
            float rs = rsqrtf(var + 1e-5f);
            unsigned yo[8];
#pragma unroll
            for (int j = 0; j < 8; j++) {
                float y0 = (g[2 * j] - mu) * rs * lgf[2 * j] + lbf[2 * j];
                float y1 = (g[2 * j + 1] - mu) * rs * lgf[2 * j + 1] + lbf[2 * j + 1];
                yo[j] = (unsigned)f2bu(y0) | ((unsigned)f2bu(y1) << 16);
            }
            uint4* yp = reinterpret_cast<uint4*>(&yls[row * YLD + c0]);
            yp[0] = make_uint4(yo[0], yo[1], yo[2], yo[3]);
            yp[1] = make_uint4(yo[4], yo[5], yo[6], yo[7]);
        }
    }
    __syncthreads();

    // ---- phase 2: GEMM y(16x1024) @ Bt^T, register-prefetched B ----
    f32x4 acc[2];
    acc[0] = (f32x4){0.f, 0.f, 0.f, 0.f};
    acc[1] = (f32x4){0.f, 0.f, 0.f, 0.f};
    for (int ko = 0; ko < 1024; ko += 32) {
        *reinterpret_cast<uint4*>(&Bls[b0row * PLDA + bkc * 8]) = pb0;
        *reinterpret_cast<uint4*>(&Bls[b1row * PLDA + bkc * 8]) = pb1;
        __syncthreads();
        int kn = ko + 32;
        if (kn < 1024) {
            pb0 = *reinterpret_cast<const uint4*>(Bt + (size_t)b0row * 1024 + kn + bkc * 8);
            pb1 = *reinterpret_cast<const uint4*>(Bt + (size_t)b1row * 1024 + kn + bkc * 8);
        }
        short8 af = *reinterpret_cast<const short8*>(&yls[l16 * YLD + ko + quad * 8]);
#pragma unroll
        for (int nt = 0; nt < 2; nt++) {
            short8 bf = *reinterpret_cast<const short8*>(&Bls[(wave * 32 + nt * 16 + l16) * PLDA + quad * 8]);
            acc[nt] = __builtin_amdgcn_mfma_f32_16x16x32_bf16(af, bf, acc[nt], 0, 0, 0);
        }
        __syncthreads();
    }
#pragma unroll
    for (int r = 0; r < 4; r++) {
        int row = m0 + quad * 4 + r;   // always < NN (1250*16 = NN)
#pragma unroll
        for (int nt = 0; nt < 2; nt++) {
            int col = wave * 32 + nt * 16 + l16;
            float v = acc[nt][r] + bu2f(bias[col]) + bu2f(resid[(size_t)row * D_H + col]);
            float rr2 = (v == v) ? fmaxf(v, 0.f) : v;  // NaN-preserving relu
            if (fp32out) ((float*)C)[(size_t)row * D_H + col] = rr2;
            else         ((u16*)C)[(size_t)row * D_H + col] = f2bu(rr2);
        }
    }
}

// ---------------- host launch ----------------
extern "C" void kernel_launch(void* const* d_in, const int* in_sizes, int n_in,
                              void* d_out, int out_size, void* d_ws, size_t ws_size,
                              hipStream_t stream) {
    const int* ei = (const int*)d_in[1];
    const int* srcI = ei;
    const int* dstI = ei + NE;

    char* w = (char*)d_ws;
    auto carve = [&](size_t bytes) -> char* {
        char* p = w;
        w += (bytes + 255) & ~(size_t)255;
        return p;
    };
    u16* Bmain  = (u16*)carve((size_t)N_LAYERS * 2048 * 128 * 2);
    u16* WvT    = (u16*)carve((size_t)N_LAYERS * 1024 * 128 * 2);
    u16* WTp    = (u16*)carve((size_t)N_LAYERS * 128 * 1024 * 2);
    u16* hA     = (u16*)carve((size_t)M_PAD * D_H * 2);
    u16* hB     = (u16*)carve((size_t)M_PAD * D_H * 2);
    u16* qkvs2  = (u16*)carve((size_t)M_PAD * QS2 * 2);
    u16* obuf   = (u16*)carve((size_t)M_PAD * 1024 * 2);
    u16* cbuf   = (u16*)carve((size_t)N_LAYERS * 1024 * 2);
    float* wscb = (float*)carve((size_t)N_LAYERS * 1024 * 4);
    float* cscb = (float*)carve((size_t)N_LAYERS * 8 * 4);
    int* cnt    = (int*)carve(2 * NN * 4);
    int* cursor = cnt + NN;
    int* offs   = (int*)carve((NN + 1) * 4);
    int* incl   = (int*)carve(NN * 4);
    int* bsum   = (int*)carve(128 * 4);
    int* bpre   = (int*)carve(128 * 4);
    int* srcp   = (int*)carve(NE * 4);
    int* flag   = (int*)carve(256);

    const int conv_size[13] = {NN * L_IN, L_IN * D_H, D_H,
                               N_LAYERS * D_HC, N_LAYERS * D_HC, N_LAYERS * D_HC,
                               N_LAYERS * D_HC, N_LAYERS * 3 * D_HC,
                               N_LAYERS * D_HC, N_LAYERS * D_HC, N_LAYERS * D_H,
                               N_LAYERS * D_H * D_HC, N_LAYERS * D_H * D_HC};
    const int conv_idx[13] = {0, 2, 3, 5, 7, 9, 11, 12, 13, 14, 16, 4, 6};
    CvDesc dsc;
    u16* conv[13];
    for (int i = 0; i < 13; i++) {
        conv[i] = (u16*)carve((size_t)conv_size[i] * 2);
        dsc.in[i] = d_in[conv_idx[i]];
        dsc.out[i] = conv[i];
    }

    k_detect<<<1, 256, 0, stream>>>((const u16*)d_in[0], flag);
    k_convert_all<<<(CV_TOTAL + 255) / 256, 256, 0, stream>>>(dsc, flag);
    const u16* x    = conv[0];
    const u16* Win  = conv[1];
    const u16* b_in = conv[2];
    const u16* bq   = conv[3];
    const u16* bk   = conv[4];
    const u16* bv   = conv[5];
    const u16* bsk  = conv[6];
    const u16* Wb   = conv[7];
    const u16* lng  = conv[8];
    const u16* lnb  = conv[9];
    const u16* bp   = conv[10];
    const u16* Wqb  = conv[11];
    const u16* Wkb  = conv[12];

    k_convT_vs<<<dim3(2, 32, 6), 256, 0, stream>>>(d_in[8], d_in[10], WvT, Bmain, flag);
    k_convT_proj<<<dim3(16, 2, 6), 256, 0, stream>>>(d_in[15], WTp, flag);
    k_GG<<<dim3(8, 6), 256, 0, stream>>>(Wqb, Wkb, Bmain);
    k_pre_small<<<(N_LAYERS * 2056 + 255) / 256, 256, 0, stream>>>(Wqb, Wkb, bq, bk,
                                                                   cbuf, wscb, cscb);
    k_input_proj<<<(NN * D_H) / 256, 256, 0, stream>>>(x, Win, b_in, hA);
    k_zero<<<(2 * NN + 255) / 256, 256, 0, stream>>>(cnt, 2 * NN);
    k_hist<<<(NE + 255) / 256, 256, 0, stream>>>(dstI, cnt);
    const int NB = (NN + 255) / 256;  // 79
    k_scanA<<<NB, 256, 0, stream>>>(cnt, incl, bsum);
    k_scanB<<<1, 128, 0, stream>>>(bsum, bpre, NB);
    k_scanC<<<NB, 256, 0, stream>>>(incl, bpre, offs);
    k_scatter<<<(NE + 255) / 256, 256, 0, stream>>>(dstI, srcI, offs, cursor, srcp);

    u16* hc = hA;
    u16* hn = hB;
    for (int l = 0; l < N_LAYERS; l++) {
        k_gemm<<<dim3(16, 157), 256, 0, stream>>>(hc, D_H, D_H,
                                                  Bmain + (size_t)l * 2048 * 128,
                                                  qkvs2, QS2,
                                                  cbuf + l * 1024, bsk + l * D_HC);
        k_attn2<<<(NN * 64) / 256, 256, 0, stream>>>(qkvs2, hc, offs, srcp,
                                                     wscb + l * 1024, cscb + l * 8);
        k_vproj<<<dim3(157, 8), 256, 0, stream>>>(qkvs2, WvT + (size_t)l * 1024 * 128,
                                                  bv + l * D_HC, obuf);
        int last = (l == N_LAYERS - 1);
        void* outp = last ? d_out : (void*)hn;
        k_bproj<<<NN / 16, 256, 0, stream>>>(obuf, qkvs2,
                                             Wb + (size_t)l * 3 * D_HC,
                                             lng + l * D_HC, lnb + l * D_HC,
                                             WTp + (size_t)l * 128 * 1024,
                                             outp, last ? 2 : 1,
                                             bp + l * D_H, hc, flag);
        u16* tmp = hc; hc = hn; hn = tmp;
    }
}

// Round 14
// 919.662 us; speedup vs baseline: 1.0779x; 1.0779x over previous
//
#include <hip/hip_runtime.h>
#include <stdint.h>

#define NN 20000
#define NE 160000
#define L_IN 15
#define D_H 128
#define N_HEADS 8
#define D_HC 1024
#define N_LAYERS 6
#define M_PAD 20096   // 157*128 = 628*32
#define QS2 2048      // zd|x_r interleaved row stride (u overwrites zd slot)

typedef unsigned short u16;
typedef __attribute__((ext_vector_type(8))) short short8;
typedef __attribute__((ext_vector_type(4))) float f32x4;

#define RSQRT_D 0.08838834764831845f  // 1/sqrt(128)

__device__ __forceinline__ float bu2f(u16 u) { return __uint_as_float(((unsigned)u) << 16); }
__device__ __forceinline__ u16 f2bu(float f) {
    unsigned x = __float_as_uint(f);
    return (u16)((x + 0x7fffu + ((x >> 16) & 1u)) >> 16);  // RNE
}
__device__ __forceinline__ float wred64(float v) {
#pragma unroll
    for (int m = 32; m >= 1; m >>= 1) v += __shfl_xor(v, m, 64);
    return v;
}
__device__ __forceinline__ void cvt16(const uint4& u0, const uint4& u1, float* f) {
    unsigned d[8] = {u0.x, u0.y, u0.z, u0.w, u1.x, u1.y, u1.z, u1.w};
#pragma unroll
    for (int i = 0; i < 8; i++) {
        f[2 * i]     = __uint_as_float(d[i] << 16);
        f[2 * i + 1] = __uint_as_float(d[i] & 0xffff0000u);
    }
}

// ---------------- dtype detection ----------------
__global__ void k_detect(const u16* __restrict__ xb, int* __restrict__ flag) {
    int t = threadIdx.x;
    u16 u = xb[2 * t];
    int e = (u >> 7) & 0xFF;
    int weird = (e > 150 || (e != 0 && e < 100)) ? 1 : 0;
    __shared__ int cnt;
    if (t == 0) cnt = 0;
    __syncthreads();
    atomicAdd(&cnt, weird);
    __syncthreads();
    if (t == 0) *flag = (cnt > 64) ? 1 : 0;  // 1 = inputs are fp32
}

// ---------------- fused convert (13 segments incl. Wq, Wk) ----------------
struct CvDesc { const void* in[13]; u16* out[13]; };
#define CV_TOTAL 1930976
__global__ void k_convert_all(CvDesc dsc, const int* __restrict__ flag) {
    const int sizes[13] = {NN * L_IN, L_IN * D_H, D_H,
                           N_LAYERS * D_HC, N_LAYERS * D_HC, N_LAYERS * D_HC,
                           N_LAYERS * D_HC, N_LAYERS * 3 * D_HC,
                           N_LAYERS * D_HC, N_LAYERS * D_HC, N_LAYERS * D_H,
                           N_LAYERS * D_H * D_HC, N_LAYERS * D_H * D_HC};
    int off = blockIdx.x * 256 + threadIdx.x;
    if (off >= CV_TOTAL) return;
    int seg = 0;
#pragma unroll
    for (int s = 0; s < 13; s++) {
        if (off >= sizes[s] && seg == s) { off -= sizes[s]; seg = s + 1; }
    }
    if (*flag) dsc.out[seg][off] = f2bu(((const float*)dsc.in[seg])[off]);
    else       dsc.out[seg][off] = ((const u16*)dsc.in[seg])[off];
}

__global__ void k_zero(int* __restrict__ p, int n) {
    int i = blockIdx.x * 256 + threadIdx.x;
    if (i < n) p[i] = 0;
}

// ------------- convert+transpose: Wv -> WvT, Wskip -> Bmain rows 1024.. ------
__global__ void k_convT_vs(const void* __restrict__ Wv, const void* __restrict__ Ws,
                           u16* __restrict__ WvT, u16* __restrict__ Bmain,
                           const int* __restrict__ flag) {
    __shared__ u16 tile[64][66];
    int tk = blockIdx.x, tn = blockIdx.y, l = blockIdx.z;
    int t = threadIdx.x;
    int isv = (tn < 16);
    const void* W = isv ? Wv : Ws;
    int n_off = (tn & 15) * 64;
    int r = t >> 2, c0 = (t & 3) * 16;
    size_t base = (size_t)l * 128 * 1024 + (size_t)(tk * 64 + r) * 1024 + n_off + c0;
    if (*flag) {
        const float* Wf = (const float*)W;
#pragma unroll
        for (int cc = 0; cc < 16; cc++) tile[c0 + cc][r] = f2bu(Wf[base + cc]);
    } else {
        const u16* Wh = (const u16*)W;
#pragma unroll
        for (int cc = 0; cc < 16; cc++) tile[c0 + cc][r] = Wh[base + cc];
    }
    __syncthreads();
    int i = t >> 2, j0 = (t & 3) * 16;
    u16* dst = isv ? (WvT + ((size_t)l * 1024 + n_off + i) * 128 + tk * 64 + j0)
                   : (Bmain + ((size_t)l * 2048 + 1024 + n_off + i) * 128 + tk * 64 + j0);
#pragma unroll
    for (int jj = 0; jj < 16; jj++) dst[jj] = tile[i][j0 + jj];
}

// Wp: [l][1024 k][128 n] -> WTp [l][128 n][1024 k]. grid (16, 2, 6).
__global__ void k_convT_proj(const void* __restrict__ Wp, u16* __restrict__ WT,
                             const int* __restrict__ flag) {
    __shared__ u16 tile[64][66];
    int tk = blockIdx.x, tn = blockIdx.y, l = blockIdx.z;
    int t = threadIdx.x;
    int r = t >> 2, c0 = (t & 3) * 16;
    size_t base = (size_t)l * 1024 * 128 + (size_t)(tk * 64 + r) * 128 + tn * 64 + c0;
    if (*flag) {
        const float* Wf = (const float*)Wp;
#pragma unroll
        for (int cc = 0; cc < 16; cc++) tile[c0 + cc][r] = f2bu(Wf[base + cc]);
    } else {
        const u16* Wh = (const u16*)Wp;
#pragma unroll
        for (int cc = 0; cc < 16; cc++) tile[c0 + cc][r] = Wh[base + cc];
    }
    __syncthreads();
    int i = t >> 2, j0 = (t & 3) * 16;
    u16* dst = WT + ((size_t)l * 128 + tn * 64 + i) * 1024 + tk * 64 + j0;
#pragma unroll
    for (int jj = 0; jj < 16; jj++) dst[jj] = tile[i][j0 + jj];
}

// ---------------- GG precompute: Bmain rows 0-1023 = (Wq_h Wk_h^T)^T / sqrt(d) --
__global__ void k_GG(const u16* __restrict__ Wqb, const u16* __restrict__ Wkb,
                     u16* __restrict__ Bmain) {
    int h = blockIdx.x, l = blockIdx.y;
    __shared__ __align__(16) u16 Als[128 * 32];
    __shared__ __align__(16) u16 Bls[128 * 32];
    const int t = threadIdx.x;
    const int wave = t >> 6, lane = t & 63, quad = lane >> 4, l16 = lane & 15;
    const int wm = (wave >> 1) * 64, wn = (wave & 1) * 64;
    const u16* Ab = Wqb + (size_t)l * 128 * 1024 + h * 128;
    const u16* Bb = Wkb + (size_t)l * 128 * 1024 + h * 128;
    f32x4 acc[4][4];
#pragma unroll
    for (int i = 0; i < 4; i++)
#pragma unroll
        for (int j = 0; j < 4; j++) acc[i][j] = (f32x4){0.f, 0.f, 0.f, 0.f};
    for (int ko = 0; ko < 128; ko += 32) {
#pragma unroll
        for (int c = t; c < 512; c += 256) {
            int row = c >> 2, kc = c & 3;
            *reinterpret_cast<uint4*>(&Als[row * 32 + kc * 8]) =
                *reinterpret_cast<const uint4*>(Ab + (size_t)row * 1024 + ko + kc * 8);
            *reinterpret_cast<uint4*>(&Bls[row * 32 + kc * 8]) =
                *reinterpret_cast<const uint4*>(Bb + (size_t)row * 1024 + ko + kc * 8);
        }
        __syncthreads();
        short8 af[4], bf[4];
#pragma unroll
        for (int mt = 0; mt < 4; mt++)
            af[mt] = *reinterpret_cast<const short8*>(&Als[(wm + mt * 16 + l16) * 32 + quad * 8]);
#pragma unroll
        for (int nt = 0; nt < 4; nt++)
            bf[nt] = *reinterpret_cast<const short8*>(&Bls[(wn + nt * 16 + l16) * 32 + quad * 8]);
#pragma unroll
        for (int mt = 0; mt < 4; mt++)
#pragma unroll
            for (int nt = 0; nt < 4; nt++)
                acc[mt][nt] = __builtin_amdgcn_mfma_f32_16x16x32_bf16(af[mt], bf[nt], acc[mt][nt], 0, 0, 0);
        __syncthreads();
    }
    u16* dst = Bmain + (size_t)l * 2048 * 128;
#pragma unroll
    for (int mt = 0; mt < 4; mt++)
#pragma unroll
        for (int r = 0; r < 4; r++) {
            int row = wm + mt * 16 + quad * 4 + r;  // a
#pragma unroll
            for (int nt = 0; nt < 4; nt++) {
                int col = wn + nt * 16 + l16;       // b
                dst[(size_t)(h * 128 + col) * 128 + row] = f2bu(acc[mt][nt][r] * RSQRT_D);
            }
        }
}

// ---------------- small precompute: cb, wscT ([h][a] layout), csc ----------------
__global__ void k_pre_small(const u16* __restrict__ Wqb, const u16* __restrict__ Wkb,
                            const u16* __restrict__ bq, const u16* __restrict__ bk,
                            u16* __restrict__ cb, float* __restrict__ wscT,
                            float* __restrict__ csc) {
    int gid = blockIdx.x * 256 + threadIdx.x;  // 6*2056
    if (gid >= N_LAYERS * 2056) return;
    int l = gid / 2056, r = gid % 2056;
    float acc = 0.f;
    if (r < 1024) {
        int h = r >> 7, b = r & 127;
        const u16* bqp = bq + l * D_HC + h * 128;
        const u16* wkp = Wkb + (size_t)l * 128 * 1024 + (size_t)b * 1024 + h * 128;
        for (int m = 0; m < 128; m++) acc += bu2f(bqp[m]) * bu2f(wkp[m]);
        cb[l * 1024 + r] = f2bu(acc * RSQRT_D);
    } else if (r < 2048) {
        int idx = r - 1024;          // idx = h*128 + a
        int h = idx >> 7, a = idx & 127;
        const u16* wqp = Wqb + (size_t)l * 128 * 1024 + (size_t)a * 1024 + h * 128;
        const u16* bkp = bk + l * D_HC + h * 128;
        for (int m = 0; m < 128; m++) acc += bu2f(wqp[m]) * bu2f(bkp[m]);
        wscT[l * 1024 + idx] = acc * RSQRT_D;
    } else {
        int h = r - 2048;
        const u16* bqp = bq + l * D_HC + h * 128;
        const u16* bkp = bk + l * D_HC + h * 128;
        for (int m = 0; m < 128; m++) acc += bu2f(bqp[m]) * bu2f(bkp[m]);
        csc[l * 8 + h] = acc * RSQRT_D;
    }
}

// ---------------- input projection ----------------
__global__ void k_input_proj(const u16* __restrict__ x, const u16* __restrict__ Win,
                             const u16* __restrict__ b_in, u16* __restrict__ h) {
    int gid = blockIdx.x * 256 + threadIdx.x;  // NN*128
    int n = gid >> 7, j = gid & 127;
    float acc = bu2f(b_in[j]);
#pragma unroll
    for (int i = 0; i < L_IN; i++) acc += bu2f(x[n * L_IN + i]) * bu2f(Win[i * D_H + j]);
    h[gid] = f2bu(acc);
}

// ---------------- CSR build ----------------
__global__ void k_hist(const int* __restrict__ dst, int* __restrict__ cnt) {
    int e = blockIdx.x * 256 + threadIdx.x;
    if (e < NE) atomicAdd(&cnt[dst[e]], 1);
}
__global__ void k_scanA(const int* __restrict__ cnt, int* __restrict__ incl, int* __restrict__ bsum) {
    __shared__ int s[256];
    int b = blockIdx.x, t = threadIdx.x, i = b * 256 + t;
    int v = (i < NN) ? cnt[i] : 0;
    s[t] = v;
    __syncthreads();
    for (int off = 1; off < 256; off <<= 1) {
        int u = (t >= off) ? s[t - off] : 0;
        __syncthreads();
        s[t] += u;
        __syncthreads();
    }
    if (i < NN) incl[i] = s[t];
    if (t == 255) bsum[b] = s[255];
}
__global__ void k_scanB(const int* __restrict__ bsum, int* __restrict__ bpre, int nb) {
    __shared__ int s[128];
    int t = threadIdx.x;
    int v = (t < nb) ? bsum[t] : 0;
    s[t] = v;
    __syncthreads();
    for (int off = 1; off < 128; off <<= 1) {
        int u = (t >= off) ? s[t - off] : 0;
        __syncthreads();
        s[t] += u;
        __syncthreads();
    }
    if (t < nb) bpre[t] = s[t] - v;
}
__global__ void k_scanC(const int* __restrict__ incl, const int* __restrict__ bpre, int* __restrict__ offs) {
    int b = blockIdx.x, t = threadIdx.x, i = b * 256 + t;
    if (i < NN) offs[i + 1] = incl[i] + bpre[b];
    if (i == 0) offs[0] = 0;
}
__global__ void k_scatter(const int* __restrict__ dst, const int* __restrict__ src,
                          const int* __restrict__ offs, int* __restrict__ cursor,
                          int* __restrict__ srcp) {
    int e = blockIdx.x * 256 + threadIdx.x;
    if (e < NE) {
        int d = dst[e];
        int p = offs[d] + atomicAdd(&cursor[d], 1);
        srcp[p] = src[e];
    }
}

// -------- main MFMA GEMM: C[M,2048] = h @ [GG^T | WskipT]^T + [cb|bskip] --------
// BK=64: K=128 -> 2 K-iterations (half the barrier drains vs BK=32). LDS 32 KB.
__global__ void k_gemm(const u16* __restrict__ A, int lda, int K,
                       const u16* __restrict__ Bt,
                       u16* __restrict__ C, int ldc,
                       const u16* __restrict__ bia0, const u16* __restrict__ bia1) {
    __shared__ __align__(16) u16 smem[2 * 128 * 64];  // Als | Bls, 32 KB
    u16* Als = smem;
    u16* Bls = smem + 128 * 64;
    const int m0 = blockIdx.y * 128, n0 = blockIdx.x * 128;
    const int t = threadIdx.x;
    const int wave = t >> 6, lane = t & 63, quad = lane >> 4, l16 = lane & 15;
    const int wm = (wave >> 1) * 64, wn = (wave & 1) * 64;
    f32x4 acc[4][4];
#pragma unroll
    for (int i = 0; i < 4; i++)
#pragma unroll
        for (int j = 0; j < 4; j++) acc[i][j] = (f32x4){0.f, 0.f, 0.f, 0.f};

    for (int ko = 0; ko < K; ko += 64) {
#pragma unroll
        for (int c = t; c < 1024; c += 256) {  // 128 rows x 8 chunks of 16B
            int row = c >> 3, kc = c & 7;
            *reinterpret_cast<uint4*>(&Als[row * 64 + kc * 8]) =
                *reinterpret_cast<const uint4*>(A + (size_t)(m0 + row) * lda + ko + kc * 8);
            *reinterpret_cast<uint4*>(&Bls[row * 64 + kc * 8]) =
                *reinterpret_cast<const uint4*>(Bt + (size_t)(n0 + row) * K + ko + kc * 8);
        }
        __syncthreads();
#pragma unroll
        for (int ks = 0; ks < 2; ks++) {
            short8 af[4], bf[4];
#pragma unroll
            for (int mt = 0; mt < 4; mt++)
                af[mt] = *reinterpret_cast<const short8*>(&Als[(wm + mt * 16 + l16) * 64 + ks * 32 + quad * 8]);
#pragma unroll
            for (int nt = 0; nt < 4; nt++)
                bf[nt] = *reinterpret_cast<const short8*>(&Bls[(wn + nt * 16 + l16) * 64 + ks * 32 + quad * 8]);
#pragma unroll
            for (int mt = 0; mt < 4; mt++)
#pragma unroll
                for (int nt = 0; nt < 4; nt++)
                    acc[mt][nt] = __builtin_amdgcn_mfma_f32_16x16x32_bf16(af[mt], bf[nt], acc[mt][nt], 0, 0, 0);
        }
        __syncthreads();
    }
    // epilogue: bias add, stage bf16 tile in LDS (stride 136), dwordx4 stores
    u16* outls = smem;  // reuse (need 128*136 = 34816 B <= 32768? no -> use 132)
    // 128*132*2 = 33792 B > 32768. Use stride 130: 128*130*2 = 33280 > 32768.
    // Use stride 128 with XOR-free direct: conflicts acceptable for epilogue; or
    // simply write via the same path as r12: stage at stride 136 needs 34 KB.
    // Safe choice: keep a separate small epilogue path = write through LDS rows
    // of 128 (16B-chunk aligned); 2-way-conflict pattern measured free.
#pragma unroll
    for (int mt = 0; mt < 4; mt++)
#pragma unroll
        for (int r = 0; r < 4; r++) {
            int rl = wm + mt * 16 + quad * 4 + r;
#pragma unroll
            for (int nt = 0; nt < 4; nt++) {
                int cl = wn + nt * 16 + l16;
                int col = n0 + cl;
                const u16* bp = (col < 1024) ? bia0 : bia1;
                outls[rl * 128 + cl] = f2bu(acc[mt][nt][r] + bu2f(bp[col & 1023]));
            }
        }
    __syncthreads();
#pragma unroll
    for (int c = t; c < 2048; c += 256) {
        int row = c >> 4, kc = c & 15;
        int grow = m0 + row;
        if (grow < NN)
            *reinterpret_cast<uint4*>(C + (size_t)grow * ldc + n0 + kc * 8) =
                *reinterpret_cast<const uint4*>(&outls[row * 128 + kc * 8]);
    }
}

// ---------------- attention (sc inlined): one wave per dst node ----------------
__global__ void k_attn2(u16* __restrict__ qkvs2, const u16* __restrict__ hc,
                        const int* __restrict__ offs, const int* __restrict__ srcp,
                        const float* __restrict__ wscT_l, const float* __restrict__ csc_l) {
    int gid = blockIdx.x * 256 + threadIdx.x;
    int d = gid >> 6, lane = gid & 63;
    if (d >= NN) return;
    int hh = lane >> 3, ci = (lane & 7) * 16;
    u16* zp = qkvs2 + (size_t)d * QS2 + hh * 128 + ci;
    float zf[16];
    {
        uint4 z0 = *reinterpret_cast<const uint4*>(zp);
        uint4 z1 = *reinterpret_cast<const uint4*>(zp + 8);
        cvt16(z0, z1, zf);
    }
    // inline sc: scown = csc[h] + sum_a h_d[a] * wscT[h][a]
    float scown;
    {
        const u16* hdp = hc + (size_t)d * 128 + ci;
        uint4 hd0 = *reinterpret_cast<const uint4*>(hdp);
        uint4 hd1 = *reinterpret_cast<const uint4*>(hdp + 8);
        float hdf[16];
        cvt16(hd0, hd1, hdf);
        const float* wt = wscT_l + hh * 128 + ci;
        float scp = 0.f;
#pragma unroll
        for (int j = 0; j < 16; j++) scp += hdf[j] * wt[j];
        scp += __shfl_xor(scp, 1, 64);
        scp += __shfl_xor(scp, 2, 64);
        scp += __shfl_xor(scp, 4, 64);
        scown = scp + csc_l[hh];
    }
    float u[16];
#pragma unroll
    for (int j = 0; j < 16; j++) u[j] = 0.f;
    float lrun = 0.f;

    int beg = offs[d], end = offs[d + 1];
    for (int c0 = beg; c0 < end; c0 += 64) {
        int cn = min(64, end - c0);
        int myidx = (c0 + lane < end) ? srcp[c0 + lane] : 0;
        int s = __shfl(myidx, 0, 64);
        const u16* hp = hc + (size_t)s * 128 + ci;
        uint4 a0 = *reinterpret_cast<const uint4*>(hp);
        uint4 a1 = *reinterpret_cast<const uint4*>(hp + 8);
        for (int i = 0; i < cn; i++) {
            uint4 n0 = a0, n1 = a1;
            if (i + 1 < cn) {
                int sn = __shfl(myidx, i + 1, 64);
                const u16* hpn = hc + (size_t)sn * 128 + ci;
                n0 = *reinterpret_cast<const uint4*>(hpn);
                n1 = *reinterpret_cast<const uint4*>(hpn + 8);
            }
            float hf[16];
            cvt16(a0, a1, hf);
            float p = 0.f;
#pragma unroll
            for (int j = 0; j < 16; j++) p += zf[j] * hf[j];
            p += __shfl_xor(p, 1, 64);
            p += __shfl_xor(p, 2, 64);
            p += __shfl_xor(p, 4, 64);
            float w = __expf(p + scown);
            lrun += w;
#pragma unroll
            for (int j = 0; j < 16; j++) u[j] += w * hf[j];
            a0 = n0; a1 = n1;
        }
    }
    float inv = 1.f / (lrun + 1e-16f);
    unsigned out[8];
#pragma unroll
    for (int j = 0; j < 8; j++)
        out[j] = (unsigned)f2bu(u[2 * j] * inv) | ((unsigned)f2bu(u[2 * j + 1] * inv) << 16);
    uint4* op = reinterpret_cast<uint4*>(zp);
    op[0] = make_uint4(out[0], out[1], out[2], out[3]);
    op[1] = make_uint4(out[4], out[5], out[6], out[7]);
}

// ---------------- vproj: o[d, h*128+c'] = u[d,h,:] @ Wv_h + bv ----------------
__global__ void k_vproj(const u16* __restrict__ A /*qkvs2 u-slot*/,
                        const u16* __restrict__ WvT_l, const u16* __restrict__ bv_l,
                        u16* __restrict__ obuf) {
    __shared__ __align__(16) u16 smem[128 * 136];
    u16* Als = smem;
    u16* Bls = smem + 4096;
    const int m0 = blockIdx.x * 128, h = blockIdx.y;
    const int t = threadIdx.x;
    const int wave = t >> 6, lane = t & 63, quad = lane >> 4, l16 = lane & 15;
    const int wm = (wave >> 1) * 64, wn = (wave & 1) * 64;
    f32x4 acc[4][4];
#pragma unroll
    for (int i = 0; i < 4; i++)
#pragma unroll
        for (int j = 0; j < 4; j++) acc[i][j] = (f32x4){0.f, 0.f, 0.f, 0.f};

    for (int ko = 0; ko < 128; ko += 32) {
#pragma unroll
        for (int c = t; c < 512; c += 256) {
            int row = c >> 2, kc = c & 3;
            *reinterpret_cast<uint4*>(&Als[row * 32 + kc * 8]) =
                *reinterpret_cast<const uint4*>(A + (size_t)(m0 + row) * QS2 + h * 128 + ko + kc * 8);
            *reinterpret_cast<uint4*>(&Bls[row * 32 + kc * 8]) =
                *reinterpret_cast<const uint4*>(WvT_l + (size_t)(h * 128 + row) * 128 + ko + kc * 8);
        }
        __syncthreads();
        short8 af[4], bf[4];
#pragma unroll
        for (int mt = 0; mt < 4; mt++)
            af[mt] = *reinterpret_cast<const short8*>(&Als[(wm + mt * 16 + l16) * 32 + quad * 8]);
#pragma unroll
        for (int nt = 0; nt < 4; nt++)
            bf[nt] = *reinterpret_cast<const short8*>(&Bls[(wn + nt * 16 + l16) * 32 + quad * 8]);
#pragma unroll
        for (int mt = 0; mt < 4; mt++)
#pragma unroll
            for (int nt = 0; nt < 4; nt++)
                acc[mt][nt] = __builtin_amdgcn_mfma_f32_16x16x32_bf16(af[mt], bf[nt], acc[mt][nt], 0, 0, 0);
        __syncthreads();
    }
#pragma unroll
    for (int mt = 0; mt < 4; mt++)
#pragma unroll
        for (int r = 0; r < 4; r++) {
            int rl = wm + mt * 16 + quad * 4 + r;
#pragma unroll
            for (int nt = 0; nt < 4; nt++) {
                int cl = wn + nt * 16 + l16;
                smem[rl * 136 + cl] = f2bu(acc[mt][nt][r] + bu2f(bv_l[h * 128 + cl]));
            }
        }
    __syncthreads();
#pragma unroll
    for (int c = t; c < 2048; c += 256) {
        int row = c >> 4, kc = c & 15;
        int grow = m0 + row;
        if (grow < NN)
            *reinterpret_cast<uint4*>(obuf + (size_t)grow * 1024 + h * 128 + kc * 8) =
                *reinterpret_cast<const uint4*>(&smem[row * 136 + kc * 8]);
    }
}

// ---------------- beta gate + LayerNorm: one wave per node ----------------
__global__ void k_betaLN(const u16* __restrict__ obuf, u16* __restrict__ qkvs2,
                         const u16* __restrict__ Wb, const u16* __restrict__ lng,
                         const u16* __restrict__ lnb) {
    int gid = blockIdx.x * 256 + threadIdx.x;
    int d = gid >> 6, lane = gid & 63;
    if (d >= NN) return;
    int c0 = lane * 16;
    float o[16], xr[16];
    {
        const u16* op = obuf + (size_t)d * 1024 + c0;
        uint4 o0 = *reinterpret_cast<const uint4*>(op);
        uint4 o1 = *reinterpret_cast<const uint4*>(op + 8);
        cvt16(o0, o1, o);
        const u16* xp = qkvs2 + (size_t)d * QS2 + 1024 + c0;
        uint4 x0 = *reinterpret_cast<const uint4*>(xp);
        uint4 x1 = *reinterpret_cast<const uint4*>(xp + 8);
        cvt16(x0, x1, xr);
    }
    float part = 0.f;
    {
        const u16* wp = Wb + c0;
        uint4 u0 = *reinterpret_cast<const uint4*>(wp);
        uint4 u1 = *reinterpret_cast<const uint4*>(wp + 8);
        float wf[16];
        cvt16(u0, u1, wf);
#pragma unroll
        for (int j = 0; j < 16; j++) part += o[j] * wf[j];
        u0 = *reinterpret_cast<const uint4*>(wp + D_HC);
        u1 = *reinterpret_cast<const uint4*>(wp + D_HC + 8);
        cvt16(u0, u1, wf);
#pragma unroll
        for (int j = 0; j < 16; j++) part += xr[j] * wf[j];
        u0 = *reinterpret_cast<const uint4*>(wp + 2 * D_HC);
        u1 = *reinterpret_cast<const uint4*>(wp + 2 * D_HC + 8);
        cvt16(u0, u1, wf);
#pragma unroll
        for (int j = 0; j < 16; j++) part += (o[j] - xr[j]) * wf[j];
    }
    float logit = wred64(part);
    float beta = 1.f / (1.f + __expf(-logit));
    float g[16], s1 = 0.f, s2 = 0.f;
#pragma unroll
    for (int j = 0; j < 16; j++) {
        g[j] = beta * xr[j] + (1.f - beta) * o[j];
        s1 += g[j]; s2 += g[j] * g[j];
    }
    s1 = wred64(s1);
    s2 = wred64(s2);
    float mu = s1 * (1.f / 1024.f);
    float var = s2 * (1.f / 1024.f) - mu * mu;
    float rs = rsqrtf(var + 1e-5f);
    {
        const u16* gp = lng + c0;
        const u16* bp2 = lnb + c0;
        uint4 g0 = *reinterpret_cast<const uint4*>(gp);
        uint4 g1 = *reinterpret_cast<const uint4*>(gp + 8);
        uint4 b0 = *reinterpret_cast<const uint4*>(bp2);
        uint4 b1 = *reinterpret_cast<const uint4*>(bp2 + 8);
        float lgf[16], lbf[16];
        cvt16(g0, g1, lgf);
        cvt16(b0, b1, lbf);
        unsigned out[8];
#pragma unroll
        for (int j = 0; j < 8; j++) {
            float y0 = (g[2 * j] - mu) * rs * lgf[2 * j] + lbf[2 * j];
            float y1 = (g[2 * j + 1] - mu) * rs * lgf[2 * j + 1] + lbf[2 * j + 1];
            out[j] = (unsigned)f2bu(y0) | ((unsigned)f2bu(y1) << 16);
        }
        uint4* yp = reinterpret_cast<uint4*>(qkvs2 + (size_t)d * QS2 + c0);
        yp[0] = make_uint4(out[0], out[1], out[2], out[3]);
        yp[1] = make_uint4(out[4], out[5], out[6], out[7]);
    }
}

// ---------------- proj GEMM v2: M=32 tiles (628 blocks) + register-prefetch ----
#define PLDA 40
__global__ void k_proj(const u16* __restrict__ A, int lda,
                       const u16* __restrict__ Bt,
                       void* __restrict__ C, int mode,
                       const u16* __restrict__ bias, const u16* __restrict__ resid,
                       const int* __restrict__ flag) {
    __shared__ __align__(16) u16 Als[32 * PLDA];
    __shared__ __align__(16) u16 Bls[128 * PLDA];
    const int m0 = blockIdx.x * 32;
    const int t = threadIdx.x;
    const int wave = t >> 6, lane = t & 63, quad = lane >> 4, l16 = lane & 15;
    const int fp32out = (mode == 2 && *flag) ? 1 : 0;
    f32x4 acc[2][2];
#pragma unroll
    for (int i = 0; i < 2; i++)
#pragma unroll
        for (int j = 0; j < 2; j++) acc[i][j] = (f32x4){0.f, 0.f, 0.f, 0.f};

    uint4 pa, pb0, pb1;
    const int arow = t >> 2, akc = t & 3;
    const int b0row = t >> 2, b0kc = t & 3;
    const int b1row = (t + 256) >> 2, b1kc = t & 3;
    {
        if (t < 128)
            pa = *reinterpret_cast<const uint4*>(A + (size_t)(m0 + arow) * lda + akc * 8);
        pb0 = *reinterpret_cast<const uint4*>(Bt + (size_t)b0row * 1024 + b0kc * 8);
        pb1 = *reinterpret_cast<const uint4*>(Bt + (size_t)b1row * 1024 + b1kc * 8);
    }
    for (int ko = 0; ko < 1024; ko += 32) {
        if (t < 128)
            *reinterpret_cast<uint4*>(&Als[arow * PLDA + akc * 8]) = pa;
        *reinterpret_cast<uint4*>(&Bls[b0row * PLDA + b0kc * 8]) = pb0;
        *reinterpret_cast<uint4*>(&Bls[b1row * PLDA + b1kc * 8]) = pb1;
        __syncthreads();
        int kn = ko + 32;
        if (kn < 1024) {
            if (t < 128)
                pa = *reinterpret_cast<const uint4*>(A + (size_t)(m0 + arow) * lda + kn + akc * 8);
            pb0 = *reinterpret_cast<const uint4*>(Bt + (size_t)b0row * 1024 + kn + b0kc * 8);
            pb1 = *reinterpret_cast<const uint4*>(Bt + (size_t)b1row * 1024 + kn + b1kc * 8);
        }
        short8 af[2], bf[2];
#pragma unroll
        for (int mt = 0; mt < 2; mt++)
            af[mt] = *reinterpret_cast<const short8*>(&Als[(mt * 16 + l16) * PLDA + quad * 8]);
#pragma unroll
        for (int nt = 0; nt < 2; nt++)
            bf[nt] = *reinterpret_cast<const short8*>(&Bls[(wave * 32 + nt * 16 + l16) * PLDA + quad * 8]);
#pragma unroll
        for (int mt = 0; mt < 2; mt++)
#pragma unroll
            for (int nt = 0; nt < 2; nt++)
                acc[mt][nt] = __builtin_amdgcn_mfma_f32_16x16x32_bf16(af[mt], bf[nt], acc[mt][nt], 0, 0, 0);
        __syncthreads();
    }
#pragma unroll
    for (int mt = 0; mt < 2; mt++)
#pragma unroll
    for (int r = 0; r < 4; r++) {
        int row = m0 + mt * 16 + quad * 4 + r;
        if (row >= NN) continue;
#pragma unroll
        for (int nt = 0; nt < 2; nt++) {
            int col = wave * 32 + nt * 16 + l16;
            float v = acc[mt][nt][r] + bu2f(bias[col]) + bu2f(resid[(size_t)row * D_H + col]);
            float rr = (v == v) ? fmaxf(v, 0.f) : v;
            if (fp32out) ((float*)C)[(size_t)row * D_H + col] = rr;
            else         ((u16*)C)[(size_t)row * D_H + col] = f2bu(rr);
        }
    }
}

// ---------------- host launch ----------------
extern "C" void kernel_launch(void* const* d_in, const int* in_sizes, int n_in,
                              void* d_out, int out_size, void* d_ws, size_t ws_size,
                              hipStream_t stream) {
    const int* ei = (const int*)d_in[1];
    const int* srcI = ei;
    const int* dstI = ei + NE;

    char* w = (char*)d_ws;
    auto carve = [&](size_t bytes) -> char* {
        char* p = w;
        w += (bytes + 255) & ~(size_t)255;
        return p;
    };
    u16* Bmain  = (u16*)carve((size_t)N_LAYERS * 2048 * 128 * 2);
    u16* WvT    = (u16*)carve((size_t)N_LAYERS * 1024 * 128 * 2);
    u16* WTp    = (u16*)carve((size_t)N_LAYERS * 128 * 1024 * 2);
    u16* hA     = (u16*)carve((size_t)M_PAD * D_H * 2);
    u16* hB     = (u16*)carve((size_t)M_PAD * D_H * 2);
    u16* qkvs2  = (u16*)carve((size_t)M_PAD * QS2 * 2);
    u16* obuf   = (u16*)carve((size_t)M_PAD * 1024 * 2);
    u16* cbuf   = (u16*)carve((size_t)N_LAYERS * 1024 * 2);
    float* wscb = (float*)carve((size_t)N_LAYERS * 1024 * 4);
    float* cscb = (float*)carve((size_t)N_LAYERS * 8 * 4);
    int* cnt    = (int*)carve(2 * NN * 4);
    int* cursor = cnt + NN;
    int* offs   = (int*)carve((NN + 1) * 4);
    int* incl   = (int*)carve(NN * 4);
    int* bsum   = (int*)carve(128 * 4);
    int* bpre   = (int*)carve(128 * 4);
    int* srcp   = (int*)carve(NE * 4);
    int* flag   = (int*)carve(256);

    const int conv_size[13] = {NN * L_IN, L_IN * D_H, D_H,
                               N_LAYERS * D_HC, N_LAYERS * D_HC, N_LAYERS * D_HC,
                               N_LAYERS * D_HC, N_LAYERS * 3 * D_HC,
                               N_LAYERS * D_HC, N_LAYERS * D_HC, N_LAYERS * D_H,
                               N_LAYERS * D_H * D_HC, N_LAYERS * D_H * D_HC};
    const int conv_idx[13] = {0, 2, 3, 5, 7, 9, 11, 12, 13, 14, 16, 4, 6};
    CvDesc dsc;
    u16* conv[13];
    for (int i = 0; i < 13; i++) {
        conv[i] = (u16*)carve((size_t)conv_size[i] * 2);
        dsc.in[i] = d_in[conv_idx[i]];
        dsc.out[i] = conv[i];
    }

    k_detect<<<1, 256, 0, stream>>>((const u16*)d_in[0], flag);
    k_convert_all<<<(CV_TOTAL + 255) / 256, 256, 0, stream>>>(dsc, flag);
    const u16* x    = conv[0];
    const u16* Win  = conv[1];
    const u16* b_in = conv[2];
    const u16* bq   = conv[3];
    const u16* bk   = conv[4];
    const u16* bv   = conv[5];
    const u16* bsk  = conv[6];
    const u16* Wb   = conv[7];
    const u16* lng  = conv[8];
    const u16* lnb  = conv[9];
    const u16* bp   = conv[10];
    const u16* Wqb  = conv[11];
    const u16* Wkb  = conv[12];

    k_convT_vs<<<dim3(2, 32, 6), 256, 0, stream>>>(d_in[8], d_in[10], WvT, Bmain, flag);
    k_convT_proj<<<dim3(16, 2, 6), 256, 0, stream>>>(d_in[15], WTp, flag);
    k_GG<<<dim3(8, 6), 256, 0, stream>>>(Wqb, Wkb, Bmain);
    k_pre_small<<<(N_LAYERS * 2056 + 255) / 256, 256, 0, stream>>>(Wqb, Wkb, bq, bk,
                                                                   cbuf, wscb, cscb);
    k_input_proj<<<(NN * D_H) / 256, 256, 0, stream>>>(x, Win, b_in, hA);
    k_zero<<<(2 * NN + 255) / 256, 256, 0, stream>>>(cnt, 2 * NN);
    k_hist<<<(NE + 255) / 256, 256, 0, stream>>>(dstI, cnt);
    const int NB = (NN + 255) / 256;  // 79
    k_scanA<<<NB, 256, 0, stream>>>(cnt, incl, bsum);
    k_scanB<<<1, 128, 0, stream>>>(bsum, bpre, NB);
    k_scanC<<<NB, 256, 0, stream>>>(incl, bpre, offs);
    k_scatter<<<(NE + 255) / 256, 256, 0, stream>>>(dstI, srcI, offs, cursor, srcp);

    u16* hc = hA;
    u16* hn = hB;
    for (int l = 0; l < N_LAYERS; l++) {
        k_gemm<<<dim3(16, 157), 256, 0, stream>>>(hc, D_H, D_H,
                                                  Bmain + (size_t)l * 2048 * 128,
                                                  qkvs2, QS2,
                                                  cbuf + l * 1024, bsk + l * D_HC);
        k_attn2<<<(NN * 64) / 256, 256, 0, stream>>>(qkvs2, hc, offs, srcp,
                                                     wscb + l * 1024, cscb + l * 8);
        k_vproj<<<dim3(157, 8), 256, 0, stream>>>(qkvs2, WvT + (size_t)l * 1024 * 128,
                                                  bv + l * D_HC, obuf);
        k_betaLN<<<(NN * 64) / 256, 256, 0, stream>>>(obuf, qkvs2,
                                                      Wb + (size_t)l * 3 * D_HC,
                                                      lng + l * D_HC, lnb + l * D_HC);
        int last = (l == N_LAYERS - 1);
        void* outp = last ? d_out : (void*)hn;
        k_proj<<<628, 256, 0, stream>>>(qkvs2, QS2, WTp + (size_t)l * 128 * 1024,
                                        outp, last ? 2 : 1,
                                        bp + l * D_H, hc, flag);
        u16* tmp = hc; hc = hn; hn = tmp;
    }
}